// Round 1
// baseline (1750.711 us; speedup 1.0000x reference)
//
#include <hip/hip_runtime.h>

#define T_ 300
#define C_ 128
#define H_ 256

typedef _Float16 f16;
typedef _Float16 f16x8 __attribute__((ext_vector_type(8)));
typedef _Float16 f16x4 __attribute__((ext_vector_type(4)));
typedef float f32x4 __attribute__((ext_vector_type(4)));

#define MFMA16(a, b, c) __builtin_amdgcn_mfma_f32_16x16x32_f16((a), (b), (c), 0, 0, 0)

__device__ __forceinline__ float sigm(float x) {
    return __fdividef(1.f, 1.f + __expf(-x));
}
__device__ __forceinline__ float tanhx(float x) {
    return __fdividef(2.f, 1.f + __expf(-2.f * x)) - 1.f;
}

// ---------------- K0: weight conversion / pre-swizzle ----------------
__global__ void k_prep(const float* __restrict__ Wih, const float* __restrict__ Whh,
                       const float* __restrict__ bih, const float* __restrict__ bhh,
                       f16* __restrict__ wlds, f16* __restrict__ whhswz,
                       f16* __restrict__ wihswz, float* __restrict__ bsum)
{
    int i = blockIdx.x * 256 + threadIdx.x;
    if (i < 8192) {
        // W_hh k<64 portion, linear [col][64] (staged to LDS by k_lstm)
        int col = i >> 3, k0 = (i & 7) * 8;
#pragma unroll
        for (int j = 0; j < 8; j++) wlds[col * 64 + k0 + j] = (f16)Whh[col * 256 + k0 + j];
    } else if (i < 32768) {
        // W_hh kf2..7 pre-swizzled per (wave, ntile, kfi, lane): 16B per lane, coalesced loads in k_lstm
        int q = i - 8192; int l = q & 63; q >>= 6;
        int kfi = q % 6; q /= 6; int nt = q & 7; int w = q >> 3;
        int col = 256 * (nt >> 1) + 32 * w + 16 * (nt & 1) + (l & 15);
        int k = (kfi + 2) * 32 + 8 * (l >> 4);
        f16* dst = whhswz + (((size_t)(w * 8 + nt) * 6 + kfi) * 64 + l) * 8;
#pragma unroll
        for (int j = 0; j < 8; j++) dst[j] = (f16)Whh[col * 256 + k + j];
    } else if (i < 49152) {
        // W_ih kf0..3 pre-swizzled
        int q = i - 32768; int l = q & 63; q >>= 6;
        int kfi = q & 3; q >>= 2; int nt = q & 7; int w = q >> 3;
        int col = 256 * (nt >> 1) + 32 * w + 16 * (nt & 1) + (l & 15);
        int k = kfi * 32 + 8 * (l >> 4);
        f16* dst = wihswz + (((size_t)(w * 8 + nt) * 4 + kfi) * 64 + l) * 8;
#pragma unroll
        for (int j = 0; j < 8; j++) dst[j] = (f16)Wih[col * 128 + k + j];
    } else if (i < 50176) {
        int j = i - 49152;
        bsum[j] = bih[j] + bhh[j];
    }
}

// ---------------- K1: fused LSTM (32 WGs x 512 thr; 1 WG per 16 sequences) ----------------
// LDS: [0,131072)   W_hh k<64, [1024 cols][64 k] f16, XOR-swizzled
//      [131072,147456) h double buffer, 2 x [16 seq][256 j] f16, XOR-swizzled
//      [147456,151552) d staging, [16 seq][128 c] f16, XOR-swizzled
__global__ __launch_bounds__(512, 2)
void k_lstm(const float* __restrict__ x, const f16* __restrict__ wlds_src,
            const f16* __restrict__ whhswz, const f16* __restrict__ wihswz,
            const float* __restrict__ bsum, f16* __restrict__ xpbuf,
            float* __restrict__ feat, int CH)
{
    extern __shared__ char lds[];
    const int tid = threadIdx.x, lane = tid & 63, w = tid >> 6;
    const int wg = blockIdx.x, win = wg >> 4, sgbase = (wg & 15) * 16;
    const int c16 = lane & 15, quad = lane >> 4;

    // stage W_lds (swizzled)
#pragma unroll
    for (int cc = 0; cc < 2; cc++) {
        int col = tid * 2 + cc;
#pragma unroll
        for (int kb = 0; kb < 8; kb++) {
            f16x8 v = *(const f16x8*)(wlds_src + col * 64 + kb * 8);
            int byte = (col * 128 + kb * 16) ^ ((col & 7) << 4);
            *(f16x8*)(lds + byte) = v;
        }
    }
    // zero h buffers
    {
        f16x8 z = {0, 0, 0, 0, 0, 0, 0, 0};
        *(f16x8*)(lds + 131072 + tid * 32) = z;
        *(f16x8*)(lds + 131072 + tid * 32 + 16) = z;
    }

    float bs[8];
#pragma unroll
    for (int nt = 0; nt < 8; nt++)
        bs[nt] = bsum[256 * (nt >> 1) + 32 * w + 16 * (nt & 1) + c16];

    f16x8 wreg[32];
#pragma unroll
    for (int kfi = 0; kfi < 4; kfi++)
#pragma unroll
        for (int nt = 0; nt < 8; nt++)
            wreg[kfi * 8 + nt] = *(const f16x8*)(whhswz + (((size_t)(w * 8 + nt) * 6 + kfi) * 64 + lane) * 8);

    float cst[8] = {0, 0, 0, 0, 0, 0, 0, 0};
    float pool[8] = {0, 0, 0, 0, 0, 0, 0, 0};

    __syncthreads();

    const int a1 = win ? 299 : 154;  // active end
    const int t0 = win ? 145 : 0;    // first step == active start

    for (int cs = t0; cs < 299; cs += CH) {
        int ce = cs + CH; if (ce > 299) ce = 299;
        if (cs < a1) {
            int xe = (ce < a1) ? ce : a1;
            // swap wreg -> W_ih fragments
#pragma unroll
            for (int kfi = 0; kfi < 4; kfi++)
#pragma unroll
                for (int nt = 0; nt < 8; nt++)
                    wreg[kfi * 8 + nt] = *(const f16x8*)(wihswz + (((size_t)(w * 8 + nt) * 4 + kfi) * 64 + lane) * 8);
            // ---- x_proj precompute for steps [cs, xe) ----
            for (int s = cs; s < xe; s++) {
                __syncthreads();
                {
                    int seq = tid >> 5, cb = (tid & 31) * 4;
                    const float* xr = x + ((size_t)(sgbase + seq) * T_ + s) * C_ + cb;
                    float4 x0 = *(const float4*)xr;
                    float4 x1 = *(const float4*)(xr + C_);
                    f16x4 d4 = {(f16)(x1.x - x0.x), (f16)(x1.y - x0.y),
                                (f16)(x1.z - x0.z), (f16)(x1.w - x0.w)};
                    int byte = 147456 + ((seq * 256 + cb * 2) ^ ((seq & 7) << 4));
                    *(f16x4*)(lds + byte) = d4;
                }
                __syncthreads();
                f32x4 a[8];
#pragma unroll
                for (int nt = 0; nt < 8; nt++) a[nt] = (f32x4){0.f, 0.f, 0.f, 0.f};
#pragma unroll
                for (int kf = 0; kf < 4; kf++) {
                    int byte = 147456 + ((c16 * 256 + (kf * 32 + 8 * quad) * 2) ^ ((c16 & 7) << 4));
                    f16x8 af = *(const f16x8*)(lds + byte);
#pragma unroll
                    for (int nt = 0; nt < 8; nt++) a[nt] = MFMA16(af, wreg[kf * 8 + nt], a[nt]);
                }
                int tc = s - cs;
#pragma unroll
                for (int nt = 0; nt < 8; nt++) {
                    f16x4 o = {(f16)a[nt].x, (f16)a[nt].y, (f16)a[nt].z, (f16)a[nt].w};
                    *(f16x4*)(xpbuf + ((((size_t)wg * CH + tc) * 8 + w) * 8 + nt) * 256 + lane * 4) = o;
                }
            }
            // restore wreg -> W_hh fragments
#pragma unroll
            for (int kfi = 0; kfi < 4; kfi++)
#pragma unroll
                for (int nt = 0; nt < 8; nt++)
                    wreg[kfi * 8 + nt] = *(const f16x8*)(whhswz + (((size_t)(w * 8 + nt) * 6 + kfi) * 64 + lane) * 8);
        }
        // ---- recurrence steps [cs, ce) ----
        for (int t = cs; t < ce; t++) {
            int tdep = 0;
            asm volatile("" : "+v"(tdep));   // block loop-invariant hoisting of streamed weight loads
            const bool act = (t < a1);
            f32x4 acc[8];
            if (act) {
                int tc = t - cs;
#pragma unroll
                for (int nt = 0; nt < 8; nt++) {
                    f16x4 v = *(const f16x4*)(xpbuf + ((((size_t)wg * CH + tc) * 8 + w) * 8 + nt) * 256 + lane * 4);
                    acc[nt] = (f32x4){bs[nt] + (float)v.x, bs[nt] + (float)v.y,
                                      bs[nt] + (float)v.z, bs[nt] + (float)v.w};
                }
            } else {
#pragma unroll
                for (int nt = 0; nt < 8; nt++) acc[nt] = (f32x4){bs[nt], bs[nt], bs[nt], bs[nt]};
            }
            const int rb = 131072 + ((t + 1) & 1) * 8192;
            const int wb = 131072 + (t & 1) * 8192;
            const int abase = c16 * 512;
            const int aswz = (c16 & 7) << 4;
            // k 64..192 from registers
#pragma unroll
            for (int kf = 2; kf < 6; kf++) {
                f16x8 af = *(const f16x8*)(lds + rb + ((abase + (kf * 32 + 8 * quad) * 2) ^ aswz));
#pragma unroll
                for (int nt = 0; nt < 8; nt++) acc[nt] = MFMA16(af, wreg[(kf - 2) * 8 + nt], acc[nt]);
            }
            // k 192..224 streamed (L2-hot, pre-swizzled, coalesced)
            {
                f16x8 af = *(const f16x8*)(lds + rb + ((abase + (6 * 32 + 8 * quad) * 2) ^ aswz));
#pragma unroll
                for (int h2 = 0; h2 < 2; h2++) {
                    f16x8 sfr[4];
#pragma unroll
                    for (int q = 0; q < 4; q++) {
                        int nt = h2 * 4 + q;
                        sfr[q] = *(const f16x8*)(whhswz + (((size_t)(w * 8 + nt) * 6 + 4) * 64 + lane) * 8 + tdep);
                    }
#pragma unroll
                    for (int q = 0; q < 4; q++) acc[h2 * 4 + q] = MFMA16(af, sfr[q], acc[h2 * 4 + q]);
                }
            }
            // k 0..64 from LDS
#pragma unroll
            for (int kf = 0; kf < 2; kf++) {
                f16x8 af = *(const f16x8*)(lds + rb + ((abase + (kf * 32 + 8 * quad) * 2) ^ aswz));
#pragma unroll
                for (int nt = 0; nt < 8; nt++) {
                    int col = 256 * (nt >> 1) + 32 * w + 16 * (nt & 1) + c16;
                    f16x8 bf = *(const f16x8*)(lds + ((col * 128 + (kf * 32 + 8 * quad) * 2) ^ ((col & 7) << 4)));
                    acc[nt] = MFMA16(af, bf, acc[nt]);
                }
            }
            // k 224..256 streamed
            {
                f16x8 af = *(const f16x8*)(lds + rb + ((abase + (7 * 32 + 8 * quad) * 2) ^ aswz));
#pragma unroll
                for (int h2 = 0; h2 < 2; h2++) {
                    f16x8 sfr[4];
#pragma unroll
                    for (int q = 0; q < 4; q++) {
                        int nt = h2 * 4 + q;
                        sfr[q] = *(const f16x8*)(whhswz + (((size_t)(w * 8 + nt) * 6 + 5) * 64 + lane) * 8 + tdep);
                    }
#pragma unroll
                    for (int q = 0; q < 4; q++) acc[h2 * 4 + q] = MFMA16(af, sfr[q], acc[h2 * 4 + q]);
                }
            }
            // gate math: acc layout D[m=4*quad+r][col]; nt = gate*2 + sub
#pragma unroll
            for (int sub = 0; sub < 2; sub++) {
#pragma unroll
                for (int r = 0; r < 4; r++) {
                    float gi = acc[0 + sub][r], gf = acc[2 + sub][r];
                    float gg = acc[4 + sub][r], go = acc[6 + sub][r];
                    int ci = sub * 4 + r;
                    float c_ = sigm(gf) * cst[ci] + sigm(gi) * tanhx(gg);
                    cst[ci] = c_;
                    float h_ = sigm(go) * tanhx(c_);
                    pool[ci] += h_;
                    int m = 4 * quad + r;
                    int j = 32 * w + 16 * sub + c16;
                    int byte = wb + ((m * 512 + j * 2) ^ ((m & 7) << 4));
                    *(f16*)(lds + byte) = (f16)h_;
                }
            }
            __syncthreads();
        }
    }
    // pooled hidden -> feat (window-major concat)
#pragma unroll
    for (int sub = 0; sub < 2; sub++)
#pragma unroll
        for (int r = 0; r < 4; r++) {
            int m = 4 * quad + r;
            int j = 32 * w + 16 * sub + c16;
            feat[(size_t)(sgbase + m) * 512 + win * 256 + j] = pool[sub * 4 + r];
        }
}

// ---------------- K2: final FC ----------------
__global__ void k_fc(const float* __restrict__ feat, const float* __restrict__ Wfc,
                     const float* __restrict__ bfc, float* __restrict__ out)
{
    int b = blockIdx.x, c = threadIdx.x;
    if (c < 60) {
        const float* fr = feat + (size_t)b * 512;
        const float* wr = Wfc + (size_t)c * 512;
        float s = bfc[c];
        for (int k = 0; k < 512; k++) s += fr[k] * wr[k];
        out[b * 60 + c] = s;
    }
}

extern "C" void kernel_launch(void* const* d_in, const int* in_sizes, int n_in,
                              void* d_out, int out_size, void* d_ws, size_t ws_size,
                              hipStream_t stream)
{
    const float* x   = (const float*)d_in[0];
    const float* Wih = (const float*)d_in[1];
    const float* Whh = (const float*)d_in[2];
    const float* bih = (const float*)d_in[3];
    const float* bhh = (const float*)d_in[4];
    const float* Wfc = (const float*)d_in[5];
    const float* bfc = (const float*)d_in[6];
    float* out = (float*)d_out;

    char* p = (char*)d_ws;
    f16* wlds   = (f16*)p; p += 1024 * 64 * 2;       // 128 KB
    f16* whhswz = (f16*)p; p += 8 * 8 * 6 * 64 * 16; // 384 KB
    f16* wihswz = (f16*)p; p += 8 * 8 * 4 * 64 * 16; // 256 KB
    float* bsum = (float*)p; p += 1024 * 4;
    float* feat = (float*)p; p += 256 * 512 * 4;     // 512 KB
    f16* xpbuf  = (f16*)p;
    size_t fixed = (size_t)(p - (char*)d_ws);
    int CH = 32;
    while (CH > 1 && fixed + (size_t)32 * CH * 32768 > ws_size) CH >>= 1;

    hipFuncSetAttribute((const void*)k_lstm, hipFuncAttributeMaxDynamicSharedMemorySize, 151552);

    k_prep<<<196, 256, 0, stream>>>(Wih, Whh, bih, bhh, wlds, whhswz, wihswz, bsum);
    k_lstm<<<32, 512, 151552, stream>>>(x, wlds, whhswz, wihswz, bsum, xpbuf, feat, CH);
    k_fc<<<256, 64, 0, stream>>>(feat, Wfc, bfc, out);
}